// Round 1
// baseline (923.457 us; speedup 1.0000x reference)
//
#include <hip/hip_runtime.h>
#include <hip/hip_bf16.h>

typedef __bf16 bf16x8 __attribute__((ext_vector_type(8)));
typedef float  f32x4  __attribute__((ext_vector_type(4)));

#define MFMA16(a,b,c) __builtin_amdgcn_mfma_f32_16x16x32_bf16((a),(b),(c),0,0,0)

__device__ __forceinline__ bf16x8 cvt8(f32x4 a, f32x4 b){
  bf16x8 r;
  r[0]=(__bf16)a[0]; r[1]=(__bf16)a[1]; r[2]=(__bf16)a[2]; r[3]=(__bf16)a[3];
  r[4]=(__bf16)b[0]; r[5]=(__bf16)b[1]; r[6]=(__bf16)b[2]; r[7]=(__bf16)b[3];
  return r;
}
__device__ __forceinline__ bf16x8 ld8(const float* p){
  return cvt8(*(const f32x4*)p, *(const f32x4*)(p+4));
}
// sigmoid / tanh via v_exp + v_rcp
__device__ __forceinline__ float sigm(float x){
  return __builtin_amdgcn_rcpf(1.f + __expf(-x));
}
__device__ __forceinline__ float tanhx(float x){
  return 1.f - 2.f*__builtin_amdgcn_rcpf(1.f + __expf(2.f*x));
}

// One LSTM layer step for a 16(batch)x256(gates) tile, K=128 (x||h).
// Reads A-fragments from XH, MFMAs against in-register weight frags WF,
// register-local elementwise (gate order i,f,g,o across n-tiles g*4+wave),
// then (after a barrier separating all reads from all writes) writes
// h_new as bf16 into XH's h-region [64..127] and optionally XNEXT's
// x-region [0..63].
#define LSTM_LAYER(XH, WF, GB, C, DO_XNEXT, XNEXT)                            \
  {                                                                            \
    bf16x8 afr_[4];                                                            \
    _Pragma("unroll")                                                          \
    for (int ks=0; ks<4; ++ks)                                                 \
      afr_[ks] = *(const bf16x8*)&XH[col][ks*32 + quad*8];                     \
    f32x4 acc_[4];                                                             \
    _Pragma("unroll")                                                          \
    for (int g=0; g<4; ++g){ float bb_ = GB[g]; acc_[g] = (f32x4){bb_,bb_,bb_,bb_}; } \
    _Pragma("unroll")                                                          \
    for (int ks=0; ks<4; ++ks){                                                \
      _Pragma("unroll")                                                        \
      for (int g=0; g<4; ++g)                                                  \
        acc_[g] = MFMA16(afr_[ks], WF[g][ks], acc_[g]);                        \
    }                                                                          \
    float hnew_[4];                                                            \
    _Pragma("unroll")                                                          \
    for (int r=0; r<4; ++r){                                                   \
      float ig_ = sigm(acc_[0][r]);                                            \
      float fg_ = sigm(acc_[1][r]);                                            \
      float gg_ = tanhx(acc_[2][r]);                                           \
      float og_ = sigm(acc_[3][r]);                                            \
      float cn_ = fg_*C[r] + ig_*gg_;                                          \
      C[r] = cn_;                                                              \
      hnew_[r] = og_ * tanhx(cn_);                                             \
    }                                                                          \
    __syncthreads();  /* all waves done reading XH before anyone writes */     \
    _Pragma("unroll")                                                          \
    for (int r=0; r<4; ++r){                                                   \
      __bf16 hb_ = (__bf16)hnew_[r];                                           \
      XH[quad*4+r][64+u] = hb_;                                                \
      if (DO_XNEXT) XNEXT[quad*4+r][u] = hb_;                                  \
    }                                                                          \
  }

extern "C" __global__ void __launch_bounds__(256, 1)
seq2seq_kernel(const float* __restrict__ X,
               const float* __restrict__ Wemb, const float* __restrict__ bemb,
               const float* __restrict__ eWih, const float* __restrict__ eWhh,
               const float* __restrict__ ebih, const float* __restrict__ ebhh,
               const float* __restrict__ dWih, const float* __restrict__ dWhh,
               const float* __restrict__ dbih, const float* __restrict__ dbhh,
               const float* __restrict__ Wreg, const float* __restrict__ breg,
               float* __restrict__ out)
{
  // xh buffers: cols 0..63 = layer input (bf16), cols 64..127 = layer hidden.
  // Row pad 128->136 elems (272 B) => bank stride 4 => 2-way aliasing (free).
  __shared__ __align__(16) __bf16 XH0[16][136];
  __shared__ __align__(16) __bf16 XH1[16][136];

  const int tid  = (int)threadIdx.x;
  const int wave = tid >> 6;
  const int lane = tid & 63;
  const int col  = lane & 15;      // MFMA A-row / D-col index
  const int quad = lane >> 4;      // MFMA k-group / D-row group
  const int u    = wave*16 + col;  // hidden unit owned by this lane
  const int b0   = (int)blockIdx.x * 8;       // 8 real batch rows per WG
  const int brow = b0 + (col & 7);            // rows 8..15 mirror 0..7 (in-bounds)

  for (int i = tid; i < 16*136; i += 256){
    (&XH0[0][0])[i] = (__bf16)0.f;
    (&XH1[0][0])[i] = (__bf16)0.f;
  }

  // ---- one-time fragment loads (all stay in VGPRs) ----
  // embedding: B[k][n]=Wemb[n][k], n=u, k=quad*8+j (K=32)
  bf16x8 wembf = ld8(Wemb + u*32 + quad*8);
  const float eb = bemb[u];

  // regression head: B[k][n]=Wreg[n][k], n=col (clamped), K=64 -> 2 ksteps
  bf16x8 wr[2];
#pragma unroll
  for (int ks=0; ks<2; ++ks) wr[ks] = ld8(Wreg + (col&7)*64 + ks*32 + quad*8);
  const float rb = breg[col & 7];

  // gate weights as B-fragments: W2[k][n] = (k<64 ? Wih[n][k] : Whh[n][k-64]),
  // n = g*64 + u (wave owns n-tiles {w,4+w,8+w,12+w} -> all 4 gates of unit u)
  bf16x8 wf[2][4][4];
  float  gb[2][4];
#pragma unroll
  for (int l=0; l<2; ++l){
#pragma unroll
    for (int g=0; g<4; ++g){
      const int n = g*64 + u;
      gb[l][g] = ebih[l*256+n] + ebhh[l*256+n];
#pragma unroll
      for (int ks=0; ks<4; ++ks){
        const float* srcw = (ks < 2) ? eWih : eWhh;
        wf[l][g][ks] = ld8(srcw + ((size_t)(l*256+n))*64 + (ks&1)*32 + quad*8);
      }
    }
  }

  float c0[4] = {0,0,0,0}, c1[4] = {0,0,0,0};
  const float* xb = X + (size_t)brow*512*32 + quad*8;

  // X prefetch pipeline, depth 2 (HBM latency ~900 cyc > 1 step)
  f32x4 pa[2], pb[2];
  pa[0] = *(const f32x4*)(xb +  0); pb[0] = *(const f32x4*)(xb +  4);
  pa[1] = *(const f32x4*)(xb + 32); pb[1] = *(const f32x4*)(xb + 36);

  __syncthreads();

  // ================= encoder =================
#pragma unroll 2
  for (int t=0; t<512; ++t){
    const int sl = t & 1;
    bf16x8 ax = cvt8(pa[sl], pb[sl]);
    int tn = t + 2; if (tn >= 512) tn = 0;
    pa[sl] = *(const f32x4*)(xb + (size_t)tn*32);
    pb[sl] = *(const f32x4*)(xb + (size_t)tn*32 + 4);

    // embedding -> XH0 x-region
    f32x4 ea = (f32x4){eb, eb, eb, eb};
    ea = MFMA16(ax, wembf, ea);
#pragma unroll
    for (int r=0; r<4; ++r) XH0[quad*4+r][u] = (__bf16)ea[r];
    __syncthreads();                              // emb visible before L0 reads

    LSTM_LAYER(XH0, wf[0], gb[0], c0, 1, XH1)     // h0 -> XH0.h, XH1.x
    __syncthreads();                              // L0 writes before L1 reads
    LSTM_LAYER(XH1, wf[1], gb[1], c1, 0, XH0)     // h1 -> XH1.h
    // next-iter barriers cover remaining hazards
  }
  __syncthreads();   // final h1 writes visible

  // ---- decoder init: layer-0 input = h1_enc ----
  for (int i = tid; i < 16*64; i += 256)
    XH0[i>>6][i&63] = XH1[i>>6][64 + (i&63)];

  // reload weight fragments with decoder weights (same registers)
#pragma unroll
  for (int l=0; l<2; ++l){
#pragma unroll
    for (int g=0; g<4; ++g){
      const int n = g*64 + u;
      gb[l][g] = dbih[l*256+n] + dbhh[l*256+n];
#pragma unroll
      for (int ks=0; ks<4; ++ks){
        const float* srcw = (ks < 2) ? dWih : dWhh;
        wf[l][g][ks] = ld8(srcw + ((size_t)(l*256+n))*64 + (ks&1)*32 + quad*8);
      }
    }
  }
#pragma unroll
  for (int r=0; r<4; ++r){ c0[r]=0.f; c1[r]=0.f; }
  __syncthreads();

  // ================= decoder =================
  for (int t=0; t<48; ++t){
    LSTM_LAYER(XH0, wf[0], gb[0], c0, 1, XH1)     // h0 -> XH0.h, XH1.x
    __syncthreads();
    LSTM_LAYER(XH1, wf[1], gb[1], c1, 1, XH0)     // h1 -> XH1.h, XH0.x (feedback)
    __syncthreads();                              // h1 visible for y-read

    // y = h1 @ Wreg^T + breg  (K=64: 2 MFMAs; all waves compute, wave-local store)
    f32x4 ya = (f32x4){rb, rb, rb, rb};
#pragma unroll
    for (int ks=0; ks<2; ++ks){
      bf16x8 ah = *(const bf16x8*)&XH1[col][64 + ks*32 + quad*8];
      ya = MFMA16(ah, wr[ks], ya);
    }
    if (quad < 2 && col < 8){
#pragma unroll
      for (int r=0; r<4; ++r){
        const int b = quad*4 + r;
        out[((size_t)(b0+b)*48 + t)*8 + col] = ya[r];
      }
    }
    __syncthreads();
  }
}

extern "C" void kernel_launch(void* const* d_in, const int* in_sizes, int n_in,
                              void* d_out, int out_size, void* d_ws, size_t ws_size,
                              hipStream_t stream)
{
  (void)in_sizes; (void)n_in; (void)out_size; (void)d_ws; (void)ws_size;
  const float* X    = (const float*)d_in[0];
  // d_in[1] = X_mask (unused by reference)
  const float* Wemb = (const float*)d_in[2];
  const float* bemb = (const float*)d_in[3];
  const float* eWih = (const float*)d_in[4];
  const float* eWhh = (const float*)d_in[5];
  const float* ebih = (const float*)d_in[6];
  const float* ebhh = (const float*)d_in[7];
  const float* dWih = (const float*)d_in[8];
  const float* dWhh = (const float*)d_in[9];
  const float* dbih = (const float*)d_in[10];
  const float* dbhh = (const float*)d_in[11];
  const float* Wreg = (const float*)d_in[12];
  const float* breg = (const float*)d_in[13];
  float* out = (float*)d_out;

  seq2seq_kernel<<<dim3(256), dim3(256), 0, stream>>>(
      X, Wemb, bemb, eWih, eWhh, ebih, ebhh,
      dWih, dWhh, dbih, dbhh, Wreg, breg, out);
}

// Round 2
// 824.412 us; speedup vs baseline: 1.1201x; 1.1201x over previous
//
#include <hip/hip_runtime.h>
#include <hip/hip_bf16.h>

typedef __bf16 bf16x8 __attribute__((ext_vector_type(8)));
typedef float  f32x4  __attribute__((ext_vector_type(4)));

#define MFMA16(a,b,c) __builtin_amdgcn_mfma_f32_16x16x32_bf16((a),(b),(c),0,0,0)

__device__ __forceinline__ bf16x8 cvt8(f32x4 a, f32x4 b){
  bf16x8 r;
  r[0]=(__bf16)a[0]; r[1]=(__bf16)a[1]; r[2]=(__bf16)a[2]; r[3]=(__bf16)a[3];
  r[4]=(__bf16)b[0]; r[5]=(__bf16)b[1]; r[6]=(__bf16)b[2]; r[7]=(__bf16)b[3];
  return r;
}
__device__ __forceinline__ bf16x8 ld8(const float* p){
  return cvt8(*(const f32x4*)p, *(const f32x4*)(p+4));
}
__device__ __forceinline__ float sigm(float x){
  return __builtin_amdgcn_rcpf(1.f + __expf(-x));
}
__device__ __forceinline__ float tanhx(float x){
  return 1.f - 2.f*__builtin_amdgcn_rcpf(1.f + __expf(2.f*x));
}

struct Acc4 { f32x4 a[4]; };

// gates[16 x 256] = A(16x128, from XH rows 0..7 mirrored via col&7) @ W2 + bias
__device__ __forceinline__ Acc4 gates_mfma(const __bf16 (*XH)[136],
                                           const bf16x8 wfl[4][4],
                                           const float gbl[4],
                                           int col7, int quad){
  bf16x8 afr[4];
#pragma unroll
  for (int ks=0; ks<4; ++ks)
    afr[ks] = *(const bf16x8*)&XH[col7][ks*32 + quad*8];
  Acc4 A;
#pragma unroll
  for (int g=0; g<4; ++g){ float bb = gbl[g]; A.a[g] = (f32x4){bb,bb,bb,bb}; }
#pragma unroll
  for (int ks=0; ks<4; ++ks)
#pragma unroll
    for (int g=0; g<4; ++g)
      A.a[g] = MFMA16(afr[ks], wfl[g][ks], A.a[g]);
  return A;
}

// acc reg index for this lane's cell: r = hi*2 + ws  (ws wave-uniform, hi per-lane)
__device__ __forceinline__ float selr(const f32x4& v, int ws, int hi){
  float lo = ws ? v[1] : v[0];
  float h2 = ws ? v[3] : v[2];
  return hi ? h2 : lo;
}

extern "C" __global__ void __launch_bounds__(512, 2)
seq2seq_kernel(const float* __restrict__ X,
               const float* __restrict__ Wemb, const float* __restrict__ bemb,
               const float* __restrict__ eWih, const float* __restrict__ eWhh,
               const float* __restrict__ ebih, const float* __restrict__ ebhh,
               const float* __restrict__ dWih, const float* __restrict__ dWhh,
               const float* __restrict__ dbih, const float* __restrict__ dbhh,
               const float* __restrict__ Wreg, const float* __restrict__ breg,
               float* __restrict__ out)
{
  // 8 real batch rows; cols 0..63 = x (bf16), 64..127 = h. Row stride 136 elems
  // (68 dw): quad write-groups land on banks {0,8,16,24}+c — conflict-free.
  __shared__ __align__(16) __bf16 XH0[8][136];
  __shared__ __align__(16) __bf16 XH1[8][136];

  const int tid  = (int)threadIdx.x;
  const int w    = tid >> 6;
  const int wg   = w & 3;        // gate-tile group (unit group)
  const int ws   = w >> 2;       // row slot (0/1)
  const int lane = tid & 63;
  const int col  = lane & 15;
  const int col7 = col & 7;
  const int quad = lane >> 4;
  const int hi   = quad >> 1;    // selects acc reg pair
  const int u    = wg*16 + col;  // hidden unit owned by this lane
  const int rowh = (quad&1)*4 + hi*2 + ws;   // this lane's batch row (0..7)
  const int b0   = (int)blockIdx.x * 8;
  const int brow = b0 + col7;

  for (int i = tid; i < 8*136; i += 512){
    (&XH0[0][0])[i] = (__bf16)0.f;
    (&XH1[0][0])[i] = (__bf16)0.f;
  }

  // ---- persistent weight fragments (VGPRs) ----
  bf16x8 wembf = ld8(Wemb + u*32 + quad*8);
  const float eb = bemb[u];

  bf16x8 wr[2];
#pragma unroll
  for (int ks=0; ks<2; ++ks) wr[ks] = ld8(Wreg + col7*64 + ks*32 + quad*8);
  const float rb = breg[col7];

  bf16x8 wf[2][4][4];
  float  gb[2][4];
#pragma unroll
  for (int l=0; l<2; ++l){
#pragma unroll
    for (int g=0; g<4; ++g){
      const int n = g*64 + u;
      gb[l][g] = ebih[l*256+n] + ebhh[l*256+n];
#pragma unroll
      for (int ks=0; ks<4; ++ks){
        const float* srcw = (ks < 2) ? eWih : eWhh;
        wf[l][g][ks] = ld8(srcw + ((size_t)(l*256+n))*64 + (ks&1)*32 + quad*8);
      }
    }
  }

  float c0 = 0.f, c1 = 0.f;
  const float* xb = X + (size_t)brow*512*32 + quad*8;
  f32x4 pa[2], pb[2];

  __syncthreads();                       // zero-init visible

  if (ws == 0){
    // emb(0) + prefetch X(1),X(2)  (slot parity = t&1)
    f32x4 xa = *(const f32x4*)xb, xv = *(const f32x4*)(xb+4);
    pa[1] = *(const f32x4*)(xb+32); pb[1] = *(const f32x4*)(xb+36);
    pa[0] = *(const f32x4*)(xb+64); pb[0] = *(const f32x4*)(xb+68);
    f32x4 ea = (f32x4){eb,eb,eb,eb};
    ea = MFMA16(cvt8(xa,xv), wembf, ea);
#pragma unroll
    for (int s2=0; s2<2; ++s2){
      int rw = (quad&1)*4 + hi*2 + s2;
      float v = hi ? ea[2+s2] : ea[s2];
      XH0[rw][u] = (__bf16)v;
    }
  }
  __syncthreads();

  // ================= encoder: 3 barriers/t =================
#pragma unroll 2
  for (int t=0; t<512; ++t){
    // L0: read XH0, gates, activations (regs only)
    Acc4 A = gates_mfma(XH0, wf[0], gb[0], col7, quad);
    float gi = sigm (selr(A.a[0], ws, hi));
    float gf = sigm (selr(A.a[1], ws, hi));
    float gg = tanhx(selr(A.a[2], ws, hi));
    float go = sigm (selr(A.a[3], ws, hi));
    c0 = gf*c0 + gi*gg;
    __bf16 hb = (__bf16)(go * tanhx(c0));
    __syncthreads();                     // (1) all XH0 reads done
    if (ws == 0){
      // emb(t+1) into XH0.x + prefetch X(t+3)
      const int s = (t+1)&1;
      f32x4 ea = (f32x4){eb,eb,eb,eb};
      ea = MFMA16(cvt8(pa[s],pb[s]), wembf, ea);
      int tn = t+3; if (tn > 511) tn = 511;
      pa[s] = *(const f32x4*)(xb + (size_t)tn*32);
      pb[s] = *(const f32x4*)(xb + (size_t)tn*32 + 4);
#pragma unroll
      for (int s2=0; s2<2; ++s2){
        int rw = (quad&1)*4 + hi*2 + s2;
        float v = hi ? ea[2+s2] : ea[s2];
        XH0[rw][u] = (__bf16)v;
      }
    }
    XH0[rowh][64+u] = hb;                // h0 recurrent
    XH1[rowh][u]    = hb;                // L1 input
    __syncthreads();                     // (2) writes visible
    // L1
    A = gates_mfma(XH1, wf[1], gb[1], col7, quad);
    gi = sigm (selr(A.a[0], ws, hi));
    gf = sigm (selr(A.a[1], ws, hi));
    gg = tanhx(selr(A.a[2], ws, hi));
    go = sigm (selr(A.a[3], ws, hi));
    c1 = gf*c1 + gi*gg;
    hb = (__bf16)(go * tanhx(c1));
    __syncthreads();                     // (3) all XH1 reads done
    XH1[rowh][64+u] = hb;
  }
  __syncthreads();

  // ---- decoder init: L0 input = h1_enc; h/c per reference ----
  for (int i = tid; i < 8*64; i += 512)
    XH0[i>>6][i&63] = XH1[i>>6][64 + (i&63)];

#pragma unroll
  for (int l=0; l<2; ++l){
#pragma unroll
    for (int g=0; g<4; ++g){
      const int n = g*64 + u;
      gb[l][g] = dbih[l*256+n] + dbhh[l*256+n];
#pragma unroll
      for (int ks=0; ks<4; ++ks){
        const float* srcw = (ks < 2) ? dWih : dWhh;
        wf[l][g][ks] = ld8(srcw + ((size_t)(l*256+n))*64 + (ks&1)*32 + quad*8);
      }
    }
  }
  c0 = 0.f; c1 = 0.f;
  __syncthreads();

  // ================= decoder: 4 barriers/t =================
  for (int t=0; t<48; ++t){
    Acc4 A = gates_mfma(XH0, wf[0], gb[0], col7, quad);
    float gi = sigm (selr(A.a[0], ws, hi));
    float gf = sigm (selr(A.a[1], ws, hi));
    float gg = tanhx(selr(A.a[2], ws, hi));
    float go = sigm (selr(A.a[3], ws, hi));
    c0 = gf*c0 + gi*gg;
    __bf16 hb = (__bf16)(go * tanhx(c0));
    __syncthreads();                     // (1)
    XH0[rowh][64+u] = hb;
    XH1[rowh][u]    = hb;
    __syncthreads();                     // (2)
    A = gates_mfma(XH1, wf[1], gb[1], col7, quad);
    gi = sigm (selr(A.a[0], ws, hi));
    gf = sigm (selr(A.a[1], ws, hi));
    gg = tanhx(selr(A.a[2], ws, hi));
    go = sigm (selr(A.a[3], ws, hi));
    c1 = gf*c1 + gi*gg;
    hb = (__bf16)(go * tanhx(c1));
    __syncthreads();                     // (3)
    XH1[rowh][64+u] = hb;
    XH0[rowh][u]    = hb;                // feedback h[-1] -> next L0 input
    __syncthreads();                     // (4)
    // y = h1 @ Wreg^T + breg (wave 0 stores)
    f32x4 ya = (f32x4){rb,rb,rb,rb};
#pragma unroll
    for (int ks=0; ks<2; ++ks){
      bf16x8 ah = *(const bf16x8*)&XH1[col7][64 + ks*32 + quad*8];
      ya = MFMA16(ah, wr[ks], ya);
    }
    if (w == 0 && quad < 2 && col < 8){
#pragma unroll
      for (int r=0; r<4; ++r)
        out[((size_t)(b0 + quad*4 + r)*48 + t)*8 + col] = ya[r];
    }
  }
}

extern "C" void kernel_launch(void* const* d_in, const int* in_sizes, int n_in,
                              void* d_out, int out_size, void* d_ws, size_t ws_size,
                              hipStream_t stream)
{
  (void)in_sizes; (void)n_in; (void)out_size; (void)d_ws; (void)ws_size;
  const float* X    = (const float*)d_in[0];
  const float* Wemb = (const float*)d_in[2];
  const float* bemb = (const float*)d_in[3];
  const float* eWih = (const float*)d_in[4];
  const float* eWhh = (const float*)d_in[5];
  const float* ebih = (const float*)d_in[6];
  const float* ebhh = (const float*)d_in[7];
  const float* dWih = (const float*)d_in[8];
  const float* dWhh = (const float*)d_in[9];
  const float* dbih = (const float*)d_in[10];
  const float* dbhh = (const float*)d_in[11];
  const float* Wreg = (const float*)d_in[12];
  const float* breg = (const float*)d_in[13];
  float* out = (float*)d_out;

  seq2seq_kernel<<<dim3(256), dim3(512), 0, stream>>>(
      X, Wemb, bemb, eWih, eWhh, ebih, ebhh,
      dWih, dWhh, dbih, dbhh, Wreg, breg, out);
}

// Round 3
// 721.285 us; speedup vs baseline: 1.2803x; 1.1430x over previous
//
#include <hip/hip_runtime.h>
#include <hip/hip_bf16.h>

typedef __bf16 bf16x8 __attribute__((ext_vector_type(8)));
typedef float  f32x4  __attribute__((ext_vector_type(4)));

#define MFMA16(a,b,c) __builtin_amdgcn_mfma_f32_16x16x32_bf16((a),(b),(c),0,0,0)

__device__ __forceinline__ bf16x8 cvt8(f32x4 a, f32x4 b){
  bf16x8 r;
  r[0]=(__bf16)a[0]; r[1]=(__bf16)a[1]; r[2]=(__bf16)a[2]; r[3]=(__bf16)a[3];
  r[4]=(__bf16)b[0]; r[5]=(__bf16)b[1]; r[6]=(__bf16)b[2]; r[7]=(__bf16)b[3];
  return r;
}
__device__ __forceinline__ bf16x8 ld8(const float* p){
  return cvt8(*(const f32x4*)p, *(const f32x4*)(p+4));
}
__device__ __forceinline__ float sigm(float x){
  return __builtin_amdgcn_rcpf(1.f + __expf(-x));
}
__device__ __forceinline__ float tanhx(float x){
  return 1.f - 2.f*__builtin_amdgcn_rcpf(1.f + __expf(2.f*x));
}
// dynamic index into f32x4 (3 v_cndmask)
__device__ __forceinline__ float sel4(const f32x4& v, int q){
  float ab = (q&1) ? v[1] : v[0];
  float cd = (q&1) ? v[3] : v[2];
  return (q&2) ? cd : ab;
}

struct Acc4 { f32x4 a[4]; };

// gates[16x256] = A(16x128; M rows mirror 4 real batch rows via col&3) @ W2 + b
__device__ __forceinline__ Acc4 gates_mfma(const __bf16 (*XH)[144],
                                           const bf16x8 wfl[4][4],
                                           const float gbl[4],
                                           int row, int quad){
  bf16x8 afr[4];
#pragma unroll
  for (int ks=0; ks<4; ++ks)
    afr[ks] = *(const bf16x8*)&XH[row][ks*32 + quad*8];
  Acc4 A;
#pragma unroll
  for (int g=0; g<4; ++g){ float bb = gbl[g]; A.a[g] = (f32x4){bb,bb,bb,bb}; }
#pragma unroll
  for (int ks=0; ks<4; ++ks)
#pragma unroll
    for (int g=0; g<4; ++g)
      A.a[g] = MFMA16(afr[ks], wfl[g][ks], A.a[g]);
  return A;
}

extern "C" __global__ void __launch_bounds__(256, 2)   // 2 blocks/CU, 256 unified regs/wave
seq2seq_kernel(const float* __restrict__ X,
               const float* __restrict__ Wemb, const float* __restrict__ bemb,
               const float* __restrict__ eWih, const float* __restrict__ eWhh,
               const float* __restrict__ ebih, const float* __restrict__ ebhh,
               const float* __restrict__ dWih, const float* __restrict__ dWhh,
               const float* __restrict__ dbih, const float* __restrict__ dbhh,
               const float* __restrict__ Wreg, const float* __restrict__ breg,
               float* __restrict__ out)
{
  // 4 real batch rows; cols 0..63 = x (bf16), 64..127 = h. Row stride 144 elems
  // (72 dw == 8 mod 32): scalar h/x writes hit 32 distinct banks; b128 reads <=2-way.
  __shared__ __align__(16) __bf16 XH0[4][144];
  __shared__ __align__(16) __bf16 XH1[4][144];

  const int tid  = (int)threadIdx.x;
  const int wg   = tid >> 6;       // wave = unit-group (n-tiles g*64 + wg*16+col)
  const int lane = tid & 63;
  const int col  = lane & 15;
  const int row  = col & 3;        // batch row for A-reads / X loads
  const int quad = lane >> 4;      // this lane's elementwise batch row
  const int u    = wg*16 + col;    // hidden unit owned by this lane
  const int b0   = (int)blockIdx.x * 4;
  const int brow = b0 + row;

  for (int i = tid; i < 4*144; i += 256){
    (&XH0[0][0])[i] = (__bf16)0.f;
    (&XH1[0][0])[i] = (__bf16)0.f;
  }

  // ---- persistent weight fragments ----
  bf16x8 wembf = ld8(Wemb + u*32 + quad*8);
  const float eb = bemb[u];

  bf16x8 wr[2];
#pragma unroll
  for (int ks=0; ks<2; ++ks) wr[ks] = ld8(Wreg + (col&7)*64 + ks*32 + quad*8);
  const float rb = breg[col&7];

  bf16x8 wf[2][4][4];     // 128 regs -> expect AGPR allocation
  float  gb[2][4];
#pragma unroll
  for (int l=0; l<2; ++l){
#pragma unroll
    for (int g=0; g<4; ++g){
      const int n = g*64 + u;
      gb[l][g] = ebih[l*256+n] + ebhh[l*256+n];
#pragma unroll
      for (int ks=0; ks<4; ++ks){
        const float* srcw = (ks < 2) ? eWih : eWhh;
        wf[l][g][ks] = ld8(srcw + ((size_t)(l*256+n))*64 + (ks&1)*32 + quad*8);
      }
    }
  }

  float c0 = 0.f, c1 = 0.f;
  const float* xb = X + (size_t)brow*512*32 + quad*8;
  f32x4 pa[2], pb[2];

  __syncthreads();                       // zero-init visible before emb writes

  {
    // emb(0) + prefetch X(1)->slot1, X(2)->slot0
    f32x4 xa = *(const f32x4*)xb, xv = *(const f32x4*)(xb+4);
    pa[1] = *(const f32x4*)(xb+32); pb[1] = *(const f32x4*)(xb+36);
    pa[0] = *(const f32x4*)(xb+64); pb[0] = *(const f32x4*)(xb+68);
    f32x4 ea = (f32x4){eb,eb,eb,eb};
    ea = MFMA16(cvt8(xa,xv), wembf, ea);
    XH0[quad][u] = (__bf16)sel4(ea, quad);
  }
  __syncthreads();

  // ================= encoder: 3 barriers/t =================
#pragma unroll 2
  for (int t=0; t<512; ++t){
    Acc4 A = gates_mfma(XH0, wf[0], gb[0], row, quad);
    float gi = sigm (sel4(A.a[0], quad));
    float gf = sigm (sel4(A.a[1], quad));
    float gg = tanhx(sel4(A.a[2], quad));
    float go = sigm (sel4(A.a[3], quad));
    c0 = gf*c0 + gi*gg;
    __bf16 hb = (__bf16)(go * tanhx(c0));
    __syncthreads();                     // (1) all XH0 reads done
    {
      // emb(t+1) into XH0.x + prefetch X(t+3)
      const int s = (t+1)&1;
      f32x4 ea = (f32x4){eb,eb,eb,eb};
      ea = MFMA16(cvt8(pa[s],pb[s]), wembf, ea);
      int tn = t+3; if (tn > 511) tn = 511;
      pa[s] = *(const f32x4*)(xb + (size_t)tn*32);
      pb[s] = *(const f32x4*)(xb + (size_t)tn*32 + 4);
      XH0[quad][u] = (__bf16)sel4(ea, quad);
    }
    XH0[quad][64+u] = hb;                // h0 recurrent
    XH1[quad][u]    = hb;                // L1 input
    __syncthreads();                     // (2) writes visible
    A = gates_mfma(XH1, wf[1], gb[1], row, quad);
    gi = sigm (sel4(A.a[0], quad));
    gf = sigm (sel4(A.a[1], quad));
    gg = tanhx(sel4(A.a[2], quad));
    go = sigm (sel4(A.a[3], quad));
    c1 = gf*c1 + gi*gg;
    hb = (__bf16)(go * tanhx(c1));
    __syncthreads();                     // (3) all XH1 reads done
    XH1[quad][64+u] = hb;
  }
  __syncthreads();

  // ---- decoder init: L0 input = h1_enc; recurrent h left in place; c=0 ----
  if (tid < 256){
    int r = tid >> 6, cc = tid & 63;
    XH0[r][cc] = XH1[r][64 + cc];
  }

#pragma unroll
  for (int l=0; l<2; ++l){
#pragma unroll
    for (int g=0; g<4; ++g){
      const int n = g*64 + u;
      gb[l][g] = dbih[l*256+n] + dbhh[l*256+n];
#pragma unroll
      for (int ks=0; ks<4; ++ks){
        const float* srcw = (ks < 2) ? dWih : dWhh;
        wf[l][g][ks] = ld8(srcw + ((size_t)(l*256+n))*64 + (ks&1)*32 + quad*8);
      }
    }
  }
  c0 = 0.f; c1 = 0.f;
  __syncthreads();

  // ================= decoder: 4 barriers/t =================
  for (int t=0; t<48; ++t){
    Acc4 A = gates_mfma(XH0, wf[0], gb[0], row, quad);
    float gi = sigm (sel4(A.a[0], quad));
    float gf = sigm (sel4(A.a[1], quad));
    float gg = tanhx(sel4(A.a[2], quad));
    float go = sigm (sel4(A.a[3], quad));
    c0 = gf*c0 + gi*gg;
    __bf16 hb = (__bf16)(go * tanhx(c0));
    __syncthreads();                     // (1)
    XH0[quad][64+u] = hb;
    XH1[quad][u]    = hb;
    __syncthreads();                     // (2)
    A = gates_mfma(XH1, wf[1], gb[1], row, quad);
    gi = sigm (sel4(A.a[0], quad));
    gf = sigm (sel4(A.a[1], quad));
    gg = tanhx(sel4(A.a[2], quad));
    go = sigm (sel4(A.a[3], quad));
    c1 = gf*c1 + gi*gg;
    hb = (__bf16)(go * tanhx(c1));
    __syncthreads();                     // (3)
    XH1[quad][64+u] = hb;
    XH0[quad][u]    = hb;                // feedback h[-1] -> next L0 input
    __syncthreads();                     // (4)
    // y = h1 @ Wreg^T + breg
    f32x4 ya = (f32x4){rb,rb,rb,rb};
#pragma unroll
    for (int ks=0; ks<2; ++ks){
      bf16x8 ah = *(const bf16x8*)&XH1[row][64 + ks*32 + quad*8];
      ya = MFMA16(ah, wr[ks], ya);
    }
    if (wg == 0 && quad == 0 && col < 8){
#pragma unroll
      for (int r=0; r<4; ++r)            // acc reg r == real batch row r
        out[((size_t)(b0 + r)*48 + t)*8 + col] = ya[r];
    }
  }
}

extern "C" void kernel_launch(void* const* d_in, const int* in_sizes, int n_in,
                              void* d_out, int out_size, void* d_ws, size_t ws_size,
                              hipStream_t stream)
{
  (void)in_sizes; (void)n_in; (void)out_size; (void)d_ws; (void)ws_size;
  const float* X    = (const float*)d_in[0];
  const float* Wemb = (const float*)d_in[2];
  const float* bemb = (const float*)d_in[3];
  const float* eWih = (const float*)d_in[4];
  const float* eWhh = (const float*)d_in[5];
  const float* ebih = (const float*)d_in[6];
  const float* ebhh = (const float*)d_in[7];
  const float* dWih = (const float*)d_in[8];
  const float* dWhh = (const float*)d_in[9];
  const float* dbih = (const float*)d_in[10];
  const float* dbhh = (const float*)d_in[11];
  const float* Wreg = (const float*)d_in[12];
  const float* breg = (const float*)d_in[13];
  float* out = (float*)d_out;

  seq2seq_kernel<<<dim3(512), dim3(256), 0, stream>>>(
      X, Wemb, bemb, eWih, eWhh, ebih, ebhh,
      dWih, dWhh, dbih, dbhh, Wreg, breg, out);
}